// Round 1
// baseline (1175.102 us; speedup 1.0000x reference)
//
#include <hip/hip_runtime.h>
#include <hip/hip_bf16.h>

typedef __bf16 bf16x8 __attribute__((ext_vector_type(8)));
typedef __bf16 bf16x4 __attribute__((ext_vector_type(4)));
typedef float floatx4 __attribute__((ext_vector_type(4)));

#define LFULL 4096

// async global->LDS, 16B per lane. LDS dest must be wave-uniform base + lane*16.
__device__ __forceinline__ void gll16(const __bf16* g, __bf16* l) {
    __builtin_amdgcn_global_load_lds(
        (const __attribute__((address_space(1))) void*)g,
        (__attribute__((address_space(3))) void*)l, 16, 0, 0);
}

// C[Mc,N] = A[Mc,K](bf16) @ B[N,K](bf16)^T + bias(fp32)
//   RD=0: C -> bf16 compact chunk buffer
//   RD=1: C -> bf16 compact, R = fp32 global residual (token-slabbed rows)
//   RD=2: C -> fp32 global (token-slabbed rows), R = bf16 compact residual
//   RD=3: C -> bf16 compact: Rp[m,n] * silu(acc+bias)   (fused SwiGLU)
//   RD=4: C -> bf16 compact: decay(n) * sigmoid(acc+bias)  (QGRU remember gate)
//   RD=5: C -> bf16 compact: tanh(acc+bias)                (QGRU input)
// Compact chunk row m maps to global row (m>>sT)*LFULL + t0 + (m&(T-1)).
template <int RD>
__global__ __launch_bounds__(256) void gemm_bt(
    const __bf16* __restrict__ A, const __bf16* __restrict__ Bw,
    const float* __restrict__ bias, const void* __restrict__ Rp,
    void* __restrict__ Cp, int K, int N, int sT, int t0)
{
    __shared__ __align__(16) __bf16 As[4][128][8];   // 8 KB: chunk c=(g*128+r) at byte c*16
    __shared__ __align__(16) __bf16 Bs[4][128][8];

    const int tid  = threadIdx.x;
    const int m0   = blockIdx.y * 128;
    const int n0   = blockIdx.x * 128;
    const int wave = tid >> 6;
    const int lane = tid & 63;
    const int wm   = (wave & 1) * 64;
    const int wn   = (wave >> 1) * 64;
    const int q    = lane >> 4;
    const int ml   = lane & 15;

    // staging: thread handles chunks c0=tid (g in {0,1}) and c0+256 (g in {2,3})
    const int r0 = tid & 127;
    const int g0 = tid >> 7;
    const __bf16* ga0 = A  + (size_t)(m0 + r0) * K + g0 * 8;
    const __bf16* gb0 = Bw + (size_t)(n0 + r0) * K + g0 * 8;
    __bf16* la0 = &As[g0][r0][0];
    __bf16* la1 = &As[g0 + 2][r0][0];
    __bf16* lb0 = &Bs[g0][r0][0];
    __bf16* lb1 = &Bs[g0 + 2][r0][0];

    floatx4 acc[4][4] = {};

    for (int k0 = 0; k0 < K; k0 += 32) {
        gll16(ga0, la0);
        gll16(ga0 + 16, la1);
        gll16(gb0, lb0);
        gll16(gb0 + 16, lb1);
        ga0 += 32; gb0 += 32;
        __syncthreads();   // drains vmcnt (global_load_lds) before LDS reads

        bf16x8 af[4], bfr[4];
#pragma unroll
        for (int i = 0; i < 4; i++) {
            af[i]  = *(const bf16x8*)&As[q][wm + i * 16 + ml][0];
            bfr[i] = *(const bf16x8*)&Bs[q][wn + i * 16 + ml][0];
        }
#pragma unroll
        for (int i = 0; i < 4; i++)
#pragma unroll
            for (int j = 0; j < 4; j++)
                acc[i][j] = __builtin_amdgcn_mfma_f32_16x16x32_bf16(af[i], bfr[j], acc[i][j], 0, 0, 0);
        __syncthreads();
    }

    const int Tmask = (1 << sT) - 1;
#pragma unroll
    for (int i = 0; i < 4; i++) {
#pragma unroll
        for (int j = 0; j < 4; j++) {
            const int n = n0 + wn + j * 16 + ml;
            const float bv = bias[n];
            const float dec = (float)n * (1.0f / 2047.0f);
#pragma unroll
            for (int r = 0; r < 4; r++) {
                const int m = m0 + wm + i * 16 + q * 4 + r;
                float v = acc[i][j][r] + bv;
                if (RD == 1) {
                    const int gm = ((m >> sT) * LFULL) + t0 + (m & Tmask);
                    v += ((const float*)Rp)[(size_t)gm * N + n];
                    ((__bf16*)Cp)[(size_t)m * N + n] = (__bf16)v;
                } else if (RD == 2) {
                    v += (float)((const __bf16*)Rp)[(size_t)m * N + n];
                    const int gm = ((m >> sT) * LFULL) + t0 + (m & Tmask);
                    ((float*)Cp)[(size_t)gm * N + n] = v;
                } else if (RD == 3) {
                    // fused SwiGLU: z1 * silu(z2), z2 = acc+bias (fp32, better than bf16 roundtrip)
                    const float sl = v / (1.f + __expf(-v));
                    const float z1 = (float)((const __bf16*)Rp)[(size_t)m * N + n];
                    ((__bf16*)Cp)[(size_t)m * N + n] = (__bf16)(z1 * sl);
                } else if (RD == 4) {
                    // remember gate r = decay(n) * sigmoid(z); __expf(-v)->inf => r->0 (safe)
                    const float rr = dec / (1.f + __expf(-v));
                    ((__bf16*)Cp)[(size_t)m * N + n] = (__bf16)rr;
                } else if (RD == 5) {
                    // tanh(z); saturates safely at +-1 for large |v|
                    const float e = __expf(2.f * v);
                    const float th = 1.f - 2.f / (e + 1.f);
                    ((__bf16*)Cp)[(size_t)m * N + n] = (__bf16)th;
                } else {
                    ((__bf16*)Cp)[(size_t)m * N + n] = (__bf16)v;
                }
            }
        }
    }
}

// fp32 -> bf16 weight conversion; blockIdx.y selects one of 6 weights (2M elems each).
__global__ __launch_bounds__(256) void cvt_w(
    const float* __restrict__ s0, const float* __restrict__ s1,
    const float* __restrict__ s2, const float* __restrict__ s3,
    const float* __restrict__ s4, const float* __restrict__ s5,
    __bf16* __restrict__ dst)
{
    const float* srcs[6] = {s0, s1, s2, s3, s4, s5};
    const float* s = srcs[blockIdx.y];
    __bf16* d = dst + (size_t)blockIdx.y * 2097152;
    const int i = (blockIdx.x * 256 + threadIdx.x) * 8;
    float4 f0 = *(const float4*)(s + i);
    float4 f1 = *(const float4*)(s + i + 4);
    bf16x8 o;
    o[0] = (__bf16)f0.x; o[1] = (__bf16)f0.y; o[2] = (__bf16)f0.z; o[3] = (__bf16)f0.w;
    o[4] = (__bf16)f1.x; o[5] = (__bf16)f1.y; o[6] = (__bf16)f1.z; o[7] = (__bf16)f1.w;
    *(bf16x8*)(d + i) = o;
}

// RMSNorm over D=1024, fp32 token-slabbed input -> bf16 compact.
__global__ __launch_bounds__(256) void rmsnorm_f32in(
    const float* __restrict__ x, const float* __restrict__ g,
    __bf16* __restrict__ o, int sT, int t0)
{
    const int r = blockIdx.x;
    const int grow = ((r >> sT) * LFULL) + t0 + (r & ((1 << sT) - 1));
    const float* xr = x + (size_t)grow * 1024;
    const int tid = threadIdx.x;

    float4 v = *(const float4*)(xr + tid * 4);
    float vv[4] = {v.x, v.y, v.z, v.w};
    float ss = vv[0] * vv[0] + vv[1] * vv[1] + vv[2] * vv[2] + vv[3] * vv[3];
#pragma unroll
    for (int off = 32; off > 0; off >>= 1) ss += __shfl_down(ss, off);

    __shared__ float red[4];
    if ((tid & 63) == 0) red[tid >> 6] = ss;
    __syncthreads();
    const float tot = red[0] + red[1] + red[2] + red[3];
    const float scale = rsqrtf(tot * (1.0f / 1024.0f) + 1e-6f);

    float4 g4 = *(const float4*)(g + tid * 4);
    float gg[4] = {g4.x, g4.y, g4.z, g4.w};
    bf16x4 ov;
#pragma unroll
    for (int e = 0; e < 4; e++) ov[e] = (__bf16)(vv[e] * scale * gg[e]);
    *(bf16x4*)(o + (size_t)r * 1024 + tid * 4) = ov;
}

// RMSNorm over D=1024, bf16 compact -> bf16 compact.
__global__ __launch_bounds__(256) void rmsnorm_b16in(
    const __bf16* __restrict__ x, const float* __restrict__ g,
    __bf16* __restrict__ o)
{
    const int r = blockIdx.x;
    const __bf16* xr = x + (size_t)r * 1024;
    const int tid = threadIdx.x;

    bf16x4 v = *(const bf16x4*)(xr + tid * 4);
    float vv[4];
#pragma unroll
    for (int e = 0; e < 4; e++) vv[e] = (float)v[e];
    float ss = vv[0] * vv[0] + vv[1] * vv[1] + vv[2] * vv[2] + vv[3] * vv[3];
#pragma unroll
    for (int off = 32; off > 0; off >>= 1) ss += __shfl_down(ss, off);

    __shared__ float red[4];
    if ((tid & 63) == 0) red[tid >> 6] = ss;
    __syncthreads();
    const float tot = red[0] + red[1] + red[2] + red[3];
    const float scale = rsqrtf(tot * (1.0f / 1024.0f) + 1e-6f);

    float4 g4 = *(const float4*)(g + tid * 4);
    float gg[4] = {g4.x, g4.y, g4.z, g4.w};
    bf16x4 ov;
#pragma unroll
    for (int e = 0; e < 4; e++) ov[e] = (__bf16)(vv[e] * scale * gg[e]);
    *(bf16x4*)(o + (size_t)r * 1024 + tid * 4) = ov;
}

// ---- parallel linear-recurrence scan: h[t] = (1-r)h[t-1] + r*th ----
// r, th are precomputed in the GEMM epilogues (RD=4 / RD=5) and stored bf16.
// Pass 1: 32-step sub-chunk summaries (A = prod a, B = scan from 0), fp32.
// Vectorized: 8 h-channels per thread (bf16x8 = 16 B/lane); 256 thr cover all 2048 h.
__global__ __launch_bounds__(256) void scan_pass1(
    const __bf16* __restrict__ rr, const __bf16* __restrict__ th,
    float* __restrict__ Ach, float* __restrict__ Bch, int T)
{
    const int h0 = threadIdx.x * 8;
    const int s = blockIdx.x;                      // sub-chunk
    const int b = blockIdx.y;
    const int NSC = T >> 5;
    size_t p = ((size_t)b * T + s * 32) * 2048 + h0;
    float Aa[8], Bv[8];
#pragma unroll
    for (int e = 0; e < 8; e++) { Aa[e] = 1.f; Bv[e] = 0.f; }
    for (int t = 0; t < 32; t++, p += 2048) {
        bf16x8 rv = *(const bf16x8*)(rr + p);
        bf16x8 tv = *(const bf16x8*)(th + p);
#pragma unroll
        for (int e = 0; e < 8; e++) {
            const float r = (float)rv[e];
            const float a = 1.f - r;
            Aa[e] *= a;
            Bv[e] = a * Bv[e] + r * (float)tv[e];
        }
    }
    const size_t qq = (size_t)(b * NSC + s) * 2048 + h0;
#pragma unroll
    for (int e = 0; e < 8; e++) { Ach[qq + e] = Aa[e]; Bch[qq + e] = Bv[e]; }
}

// Pass 2: sequential composition over sub-chunk summaries; emits start-state per sub-chunk.
__global__ __launch_bounds__(256) void scan_pass2(
    const float* __restrict__ Ach, const float* __restrict__ Bch,
    float* __restrict__ hst, const float* __restrict__ hidden,
    float* __restrict__ state, float* __restrict__ hlast,
    int NSC, int first, int last)
{
    const int idx = blockIdx.x * 256 + threadIdx.x;  // 0..8191 = (b,h)
    const int b = idx >> 11;
    const int h = idx & 2047;
    float hs = first ? hidden[idx] : state[idx];
    size_t qq = (size_t)b * NSC * 2048 + h;
#pragma unroll 4
    for (int s = 0; s < NSC; s++, qq += 2048) {
        hst[qq] = hs;
        hs = Ach[qq] * hs + Bch[qq];
    }
    state[idx] = hs;
    if (last) hlast[idx] = hs;
}

// Pass 3: replay each sub-chunk from its fp32 start state; write h (bf16) over r in place.
// Vectorized: 8 h-channels per thread.
__global__ __launch_bounds__(256) void scan_pass3(
    __bf16* __restrict__ rio, const __bf16* __restrict__ th,
    const float* __restrict__ hst, int T)
{
    const int h0 = threadIdx.x * 8;
    const int s = blockIdx.x;
    const int b = blockIdx.y;
    const int NSC = T >> 5;
    float hp[8];
    const size_t qq = (size_t)(b * NSC + s) * 2048 + h0;
#pragma unroll
    for (int e = 0; e < 8; e++) hp[e] = hst[qq + e];
    size_t p = ((size_t)b * T + s * 32) * 2048 + h0;
    for (int t = 0; t < 32; t++, p += 2048) {
        bf16x8 rv = *(const bf16x8*)(rio + p);
        bf16x8 tv = *(const bf16x8*)(th + p);
        bf16x8 ov;
#pragma unroll
        for (int e = 0; e < 8; e++) {
            const float r = (float)rv[e];
            hp[e] = (1.f - r) * hp[e] + r * (float)tv[e];
            ov[e] = (__bf16)hp[e];
        }
        *(bf16x8*)(rio + p) = ov;
    }
}

extern "C" void kernel_launch(void* const* d_in, const int* in_sizes, int n_in,
                              void* d_out, int out_size, void* d_ws, size_t ws_size,
                              hipStream_t stream)
{
    const float* x        = (const float*)d_in[0];
    const float* hidden   = (const float*)d_in[1];
    const float* w_forget = (const float*)d_in[2];
    const float* b_forget = (const float*)d_in[3];
    const float* w_input  = (const float*)d_in[4];
    const float* b_input  = (const float*)d_in[5];
    const float* w_hout   = (const float*)d_in[6];
    const float* b_hout   = (const float*)d_in[7];
    const float* w_fc     = (const float*)d_in[8];
    const float* b_fc     = (const float*)d_in[9];
    const float* w_fc_act = (const float*)d_in[10];
    const float* b_fc_act = (const float*)d_in[11];
    const float* w_fout   = (const float*)d_in[12];
    const float* b_fout   = (const float*)d_in[13];
    const float* g_norm1  = (const float*)d_in[14];
    const float* g_norm2  = (const float*)d_in[15];

    float* out   = (float*)d_out;
    float* hlast = out + (size_t)16384 * 1024;

    // workspace need(T): wb 24MB + chunk activations + scan summaries + state
    int T = 4096;
    for (;;) {
        size_t need = 25165824ull + (size_t)4 * T * 12288 + 3ull * 4 * (T / 32) * 2048 * 4 + 65536;
        if (need <= ws_size || T == 256) break;
        T >>= 1;
    }
    const int NC = 4096 / T;
    int sT = 0; while ((1 << sT) < T) sT++;
    const int Mc = 4 * T;
    const int NSC = T >> 5;

    char* p = (char*)d_ws;
    __bf16* wb = (__bf16*)p; p += 25165824ull;          // 6 weights bf16, 2M elems each
    __bf16* xn = (__bf16*)p; p += (size_t)Mc * 1024 * 2;
    __bf16* zf = (__bf16*)p; p += (size_t)Mc * 2048 * 2;
    __bf16* zi = (__bf16*)p; p += (size_t)Mc * 2048 * 2;
    __bf16* x1 = (__bf16*)p; p += (size_t)Mc * 1024 * 2;
    float* Ach = (float*)p;  p += (size_t)4 * NSC * 2048 * 4;
    float* Bch = (float*)p;  p += (size_t)4 * NSC * 2048 * 4;
    float* hst = (float*)p;  p += (size_t)4 * NSC * 2048 * 4;
    float* state = (float*)p;

    __bf16* wb_f  = wb;
    __bf16* wb_i  = wb + 2097152;
    __bf16* wb_fc = wb + 2 * 2097152;
    __bf16* wb_fa = wb + 3 * 2097152;
    __bf16* wb_h  = wb + 4 * 2097152;
    __bf16* wb_o  = wb + 5 * 2097152;

    cvt_w<<<dim3(1024, 6), 256, 0, stream>>>(w_forget, w_input, w_fc, w_fc_act, w_hout, w_fout, wb);

    for (int c = 0; c < NC; c++) {
        const int t0 = c * T;
        // --- QGRU sub-block ---
        rmsnorm_f32in<<<Mc, 256, 0, stream>>>(x, g_norm1, xn, sT, t0);
        // zf <- r = decay*sigmoid(xn@Wf^T+b)   (RD=4, activation fused in epilogue)
        gemm_bt<4><<<dim3(16, Mc / 128), 256, 0, stream>>>(xn, wb_f, b_forget, nullptr, zf, 1024, 2048, sT, t0);
        // zi <- th = tanh(xn@Wi^T+b)           (RD=5)
        gemm_bt<5><<<dim3(16, Mc / 128), 256, 0, stream>>>(xn, wb_i, b_input,  nullptr, zi, 1024, 2048, sT, t0);
        scan_pass1<<<dim3(NSC, 4), 256, 0, stream>>>(zf, zi, Ach, Bch, T);
        scan_pass2<<<32, 256, 0, stream>>>(Ach, Bch, hst, hidden, state, hlast, NSC,
                                           (c == 0) ? 1 : 0, (c == NC - 1) ? 1 : 0);
        scan_pass3<<<dim3(NSC, 4), 256, 0, stream>>>(zf, zi, hst, T);
        gemm_bt<1><<<dim3(8, Mc / 128), 256, 0, stream>>>(zf, wb_h, b_hout, x, x1, 2048, 1024, sT, t0);
        // --- FFN SwiGLU sub-block ---
        rmsnorm_b16in<<<Mc, 256, 0, stream>>>(x1, g_norm2, xn);
        gemm_bt<0><<<dim3(16, Mc / 128), 256, 0, stream>>>(xn, wb_fc, b_fc,     nullptr, zf, 1024, 2048, sT, t0);
        // zf <- zf * silu(xn@Wfa^T+b)          (RD=3, SwiGLU fused; swiglu kernel eliminated)
        gemm_bt<3><<<dim3(16, Mc / 128), 256, 0, stream>>>(xn, wb_fa, b_fc_act, zf, zf, 1024, 2048, sT, t0);
        gemm_bt<2><<<dim3(8, Mc / 128), 256, 0, stream>>>(zf, wb_o, b_fout, x1, out, 2048, 1024, sT, t0);
    }
}

// Round 2
// 1114.710 us; speedup vs baseline: 1.0542x; 1.0542x over previous
//
#include <hip/hip_runtime.h>
#include <hip/hip_bf16.h>

typedef __bf16 bf16x8 __attribute__((ext_vector_type(8)));
typedef __bf16 bf16x4 __attribute__((ext_vector_type(4)));
typedef float floatx4 __attribute__((ext_vector_type(4)));

#define LFULL 4096

// async global->LDS, 16B per lane. LDS dest must be wave-uniform base + lane*16.
__device__ __forceinline__ void gll16(const __bf16* g, __bf16* l) {
    __builtin_amdgcn_global_load_lds(
        (const __attribute__((address_space(1))) void*)g,
        (__attribute__((address_space(3))) void*)l, 16, 0, 0);
}

// C[Mc,N] = A[Mc,K](bf16) @ B[N,K](bf16)^T + bias(fp32)
//   RD=0: C -> bf16 compact chunk buffer
//   RD=1: C -> bf16 compact, R = fp32 global residual (token-slabbed rows)
//   RD=2: C -> fp32 global (token-slabbed rows), R = bf16 compact residual
//   RD=3: C -> bf16 compact: Rp[m,n] * silu(acc+bias)   (fused SwiGLU)
//   RD=4: C -> bf16 compact: decay(n) * sigmoid(acc+bias)  (QGRU remember gate)
//   RD=5: C -> bf16 compact: tanh(acc+bias)                (QGRU input)
// Compact chunk row m maps to global row (m>>sT)*LFULL + t0 + (m&(T-1)).
// Double-buffered LDS (2-phase): stage tile k+1 before computing tile k; one
// barrier per K-step. XCD-bijective swizzle: each XCD owns contiguous m-tiles.
template <int RD>
__global__ __launch_bounds__(256) void gemm_bt(
    const __bf16* __restrict__ A, const __bf16* __restrict__ Bw,
    const float* __restrict__ bias, const void* __restrict__ Rp,
    void* __restrict__ Cp, int K, int N, int sT, int t0)
{
    __shared__ __align__(16) __bf16 As[2][4][128][8];   // 16 KB: [buf][kchunk][row][8]
    __shared__ __align__(16) __bf16 Bs[2][4][128][8];

    const int tid  = threadIdx.x;

    // XCD-bijective swizzle (nwg % 8 == 0 for all our launches):
    // XCD k gets a contiguous wg range = contiguous m-tiles, all n-tiles each.
    const int nwg = gridDim.x * gridDim.y;
    int bid = blockIdx.y * gridDim.x + blockIdx.x;
    bid = (bid & 7) * (nwg >> 3) + (bid >> 3);
    const int m0 = (bid / gridDim.x) * 128;
    const int n0 = (bid % gridDim.x) * 128;

    const int wave = tid >> 6;
    const int lane = tid & 63;
    const int wm   = (wave & 1) * 64;
    const int wn   = (wave >> 1) * 64;
    const int q    = lane >> 4;
    const int ml   = lane & 15;

    // staging: thread handles chunks c0=tid (g in {0,1}) and c0+256 (g in {2,3})
    const int r0 = tid & 127;
    const int g0 = tid >> 7;
    const __bf16* ga0 = A  + (size_t)(m0 + r0) * K + g0 * 8;
    const __bf16* gb0 = Bw + (size_t)(n0 + r0) * K + g0 * 8;

    floatx4 acc[4][4] = {};

#define STAGE(BUF) do { \
        gll16(ga0,      &As[BUF][g0][r0][0]); \
        gll16(ga0 + 16, &As[BUF][g0 + 2][r0][0]); \
        gll16(gb0,      &Bs[BUF][g0][r0][0]); \
        gll16(gb0 + 16, &Bs[BUF][g0 + 2][r0][0]); \
        ga0 += 32; gb0 += 32; \
    } while (0)

#define COMPUTE(BUF) do { \
        bf16x8 af[4], bfr[4]; \
        _Pragma("unroll") \
        for (int i = 0; i < 4; i++) { \
            af[i]  = *(const bf16x8*)&As[BUF][q][wm + i * 16 + ml][0]; \
            bfr[i] = *(const bf16x8*)&Bs[BUF][q][wn + i * 16 + ml][0]; \
        } \
        _Pragma("unroll") \
        for (int i = 0; i < 4; i++) \
            _Pragma("unroll") \
            for (int j = 0; j < 4; j++) \
                acc[i][j] = __builtin_amdgcn_mfma_f32_16x16x32_bf16(af[i], bfr[j], acc[i][j], 0, 0, 0); \
    } while (0)

    // K is 1024 or 2048 -> nsteps even (32 or 64)
    const int nsteps = K >> 5;
    STAGE(0);
    __syncthreads();                       // buf0 ready
    const int npairs = (nsteps - 2) >> 1;
    for (int s = 0; s < npairs; ++s) {
        STAGE(1); COMPUTE(0); __syncthreads();   // overlap: load k+1 under compute k
        STAGE(0); COMPUTE(1); __syncthreads();
    }
    STAGE(1); COMPUTE(0); __syncthreads();
    COMPUTE(1);

#undef STAGE
#undef COMPUTE

    const int Tmask = (1 << sT) - 1;
#pragma unroll
    for (int i = 0; i < 4; i++) {
#pragma unroll
        for (int j = 0; j < 4; j++) {
            const int n = n0 + wn + j * 16 + ml;
            const float bv = bias[n];
            const float dec = (float)n * (1.0f / 2047.0f);
#pragma unroll
            for (int r = 0; r < 4; r++) {
                const int m = m0 + wm + i * 16 + q * 4 + r;
                float v = acc[i][j][r] + bv;
                if (RD == 1) {
                    const int gm = ((m >> sT) * LFULL) + t0 + (m & Tmask);
                    v += ((const float*)Rp)[(size_t)gm * N + n];
                    ((__bf16*)Cp)[(size_t)m * N + n] = (__bf16)v;
                } else if (RD == 2) {
                    v += (float)((const __bf16*)Rp)[(size_t)m * N + n];
                    const int gm = ((m >> sT) * LFULL) + t0 + (m & Tmask);
                    ((float*)Cp)[(size_t)gm * N + n] = v;
                } else if (RD == 3) {
                    // fused SwiGLU: z1 * silu(z2), z2 = acc+bias (fp32, better than bf16 roundtrip)
                    const float sl = v / (1.f + __expf(-v));
                    const float z1 = (float)((const __bf16*)Rp)[(size_t)m * N + n];
                    ((__bf16*)Cp)[(size_t)m * N + n] = (__bf16)(z1 * sl);
                } else if (RD == 4) {
                    // remember gate r = decay(n) * sigmoid(z); __expf(-v)->inf => r->0 (safe)
                    const float rr = dec / (1.f + __expf(-v));
                    ((__bf16*)Cp)[(size_t)m * N + n] = (__bf16)rr;
                } else if (RD == 5) {
                    // tanh(z); saturates safely at +-1 for large |v|
                    const float e = __expf(2.f * v);
                    const float th = 1.f - 2.f / (e + 1.f);
                    ((__bf16*)Cp)[(size_t)m * N + n] = (__bf16)th;
                } else {
                    ((__bf16*)Cp)[(size_t)m * N + n] = (__bf16)v;
                }
            }
        }
    }
}

// fp32 -> bf16 weight conversion; blockIdx.y selects one of 6 weights (2M elems each).
__global__ __launch_bounds__(256) void cvt_w(
    const float* __restrict__ s0, const float* __restrict__ s1,
    const float* __restrict__ s2, const float* __restrict__ s3,
    const float* __restrict__ s4, const float* __restrict__ s5,
    __bf16* __restrict__ dst)
{
    const float* srcs[6] = {s0, s1, s2, s3, s4, s5};
    const float* s = srcs[blockIdx.y];
    __bf16* d = dst + (size_t)blockIdx.y * 2097152;
    const int i = (blockIdx.x * 256 + threadIdx.x) * 8;
    float4 f0 = *(const float4*)(s + i);
    float4 f1 = *(const float4*)(s + i + 4);
    bf16x8 o;
    o[0] = (__bf16)f0.x; o[1] = (__bf16)f0.y; o[2] = (__bf16)f0.z; o[3] = (__bf16)f0.w;
    o[4] = (__bf16)f1.x; o[5] = (__bf16)f1.y; o[6] = (__bf16)f1.z; o[7] = (__bf16)f1.w;
    *(bf16x8*)(d + i) = o;
}

// RMSNorm over D=1024, fp32 token-slabbed input -> bf16 compact.
__global__ __launch_bounds__(256) void rmsnorm_f32in(
    const float* __restrict__ x, const float* __restrict__ g,
    __bf16* __restrict__ o, int sT, int t0)
{
    const int r = blockIdx.x;
    const int grow = ((r >> sT) * LFULL) + t0 + (r & ((1 << sT) - 1));
    const float* xr = x + (size_t)grow * 1024;
    const int tid = threadIdx.x;

    float4 v = *(const float4*)(xr + tid * 4);
    float vv[4] = {v.x, v.y, v.z, v.w};
    float ss = vv[0] * vv[0] + vv[1] * vv[1] + vv[2] * vv[2] + vv[3] * vv[3];
#pragma unroll
    for (int off = 32; off > 0; off >>= 1) ss += __shfl_down(ss, off);

    __shared__ float red[4];
    if ((tid & 63) == 0) red[tid >> 6] = ss;
    __syncthreads();
    const float tot = red[0] + red[1] + red[2] + red[3];
    const float scale = rsqrtf(tot * (1.0f / 1024.0f) + 1e-6f);

    float4 g4 = *(const float4*)(g + tid * 4);
    float gg[4] = {g4.x, g4.y, g4.z, g4.w};
    bf16x4 ov;
#pragma unroll
    for (int e = 0; e < 4; e++) ov[e] = (__bf16)(vv[e] * scale * gg[e]);
    *(bf16x4*)(o + (size_t)r * 1024 + tid * 4) = ov;
}

// RMSNorm over D=1024, bf16 compact -> bf16 compact.
__global__ __launch_bounds__(256) void rmsnorm_b16in(
    const __bf16* __restrict__ x, const float* __restrict__ g,
    __bf16* __restrict__ o)
{
    const int r = blockIdx.x;
    const __bf16* xr = x + (size_t)r * 1024;
    const int tid = threadIdx.x;

    bf16x4 v = *(const bf16x4*)(xr + tid * 4);
    float vv[4];
#pragma unroll
    for (int e = 0; e < 4; e++) vv[e] = (float)v[e];
    float ss = vv[0] * vv[0] + vv[1] * vv[1] + vv[2] * vv[2] + vv[3] * vv[3];
#pragma unroll
    for (int off = 32; off > 0; off >>= 1) ss += __shfl_down(ss, off);

    __shared__ float red[4];
    if ((tid & 63) == 0) red[tid >> 6] = ss;
    __syncthreads();
    const float tot = red[0] + red[1] + red[2] + red[3];
    const float scale = rsqrtf(tot * (1.0f / 1024.0f) + 1e-6f);

    float4 g4 = *(const float4*)(g + tid * 4);
    float gg[4] = {g4.x, g4.y, g4.z, g4.w};
    bf16x4 ov;
#pragma unroll
    for (int e = 0; e < 4; e++) ov[e] = (__bf16)(vv[e] * scale * gg[e]);
    *(bf16x4*)(o + (size_t)r * 1024 + tid * 4) = ov;
}

// ---- parallel linear-recurrence scan: h[t] = (1-r)h[t-1] + r*th ----
// r, th are precomputed in the GEMM epilogues (RD=4 / RD=5) and stored bf16.
// Pass 1: 32-step sub-chunk summaries (A = prod a, B = scan from 0), fp32.
// Vectorized: 8 h-channels per thread (bf16x8 = 16 B/lane); 256 thr cover all 2048 h.
__global__ __launch_bounds__(256) void scan_pass1(
    const __bf16* __restrict__ rr, const __bf16* __restrict__ th,
    float* __restrict__ Ach, float* __restrict__ Bch, int T)
{
    const int h0 = threadIdx.x * 8;
    const int s = blockIdx.x;                      // sub-chunk
    const int b = blockIdx.y;
    const int NSC = T >> 5;
    size_t p = ((size_t)b * T + s * 32) * 2048 + h0;
    float Aa[8], Bv[8];
#pragma unroll
    for (int e = 0; e < 8; e++) { Aa[e] = 1.f; Bv[e] = 0.f; }
    for (int t = 0; t < 32; t++, p += 2048) {
        bf16x8 rv = *(const bf16x8*)(rr + p);
        bf16x8 tv = *(const bf16x8*)(th + p);
#pragma unroll
        for (int e = 0; e < 8; e++) {
            const float r = (float)rv[e];
            const float a = 1.f - r;
            Aa[e] *= a;
            Bv[e] = a * Bv[e] + r * (float)tv[e];
        }
    }
    const size_t qq = (size_t)(b * NSC + s) * 2048 + h0;
#pragma unroll
    for (int e = 0; e < 8; e++) { Ach[qq + e] = Aa[e]; Bch[qq + e] = Bv[e]; }
}

// Pass 2: sequential composition over sub-chunk summaries; emits start-state per sub-chunk.
__global__ __launch_bounds__(256) void scan_pass2(
    const float* __restrict__ Ach, const float* __restrict__ Bch,
    float* __restrict__ hst, const float* __restrict__ hidden,
    float* __restrict__ state, float* __restrict__ hlast,
    int NSC, int first, int last)
{
    const int idx = blockIdx.x * 256 + threadIdx.x;  // 0..8191 = (b,h)
    const int b = idx >> 11;
    const int h = idx & 2047;
    float hs = first ? hidden[idx] : state[idx];
    size_t qq = (size_t)b * NSC * 2048 + h;
#pragma unroll 4
    for (int s = 0; s < NSC; s++, qq += 2048) {
        hst[qq] = hs;
        hs = Ach[qq] * hs + Bch[qq];
    }
    state[idx] = hs;
    if (last) hlast[idx] = hs;
}

// Pass 3: replay each sub-chunk from its fp32 start state; write h (bf16) over r in place.
// Vectorized: 8 h-channels per thread.
__global__ __launch_bounds__(256) void scan_pass3(
    __bf16* __restrict__ rio, const __bf16* __restrict__ th,
    const float* __restrict__ hst, int T)
{
    const int h0 = threadIdx.x * 8;
    const int s = blockIdx.x;
    const int b = blockIdx.y;
    const int NSC = T >> 5;
    float hp[8];
    const size_t qq = (size_t)(b * NSC + s) * 2048 + h0;
#pragma unroll
    for (int e = 0; e < 8; e++) hp[e] = hst[qq + e];
    size_t p = ((size_t)b * T + s * 32) * 2048 + h0;
    for (int t = 0; t < 32; t++, p += 2048) {
        bf16x8 rv = *(const bf16x8*)(rio + p);
        bf16x8 tv = *(const bf16x8*)(th + p);
        bf16x8 ov;
#pragma unroll
        for (int e = 0; e < 8; e++) {
            const float r = (float)rv[e];
            hp[e] = (1.f - r) * hp[e] + r * (float)tv[e];
            ov[e] = (__bf16)hp[e];
        }
        *(bf16x8*)(rio + p) = ov;
    }
}

extern "C" void kernel_launch(void* const* d_in, const int* in_sizes, int n_in,
                              void* d_out, int out_size, void* d_ws, size_t ws_size,
                              hipStream_t stream)
{
    const float* x        = (const float*)d_in[0];
    const float* hidden   = (const float*)d_in[1];
    const float* w_forget = (const float*)d_in[2];
    const float* b_forget = (const float*)d_in[3];
    const float* w_input  = (const float*)d_in[4];
    const float* b_input  = (const float*)d_in[5];
    const float* w_hout   = (const float*)d_in[6];
    const float* b_hout   = (const float*)d_in[7];
    const float* w_fc     = (const float*)d_in[8];
    const float* b_fc     = (const float*)d_in[9];
    const float* w_fc_act = (const float*)d_in[10];
    const float* b_fc_act = (const float*)d_in[11];
    const float* w_fout   = (const float*)d_in[12];
    const float* b_fout   = (const float*)d_in[13];
    const float* g_norm1  = (const float*)d_in[14];
    const float* g_norm2  = (const float*)d_in[15];

    float* out   = (float*)d_out;
    float* hlast = out + (size_t)16384 * 1024;

    // workspace need(T): wb 24MB + chunk activations + scan summaries + state
    int T = 4096;
    for (;;) {
        size_t need = 25165824ull + (size_t)4 * T * 12288 + 3ull * 4 * (T / 32) * 2048 * 4 + 65536;
        if (need <= ws_size || T == 256) break;
        T >>= 1;
    }
    const int NC = 4096 / T;
    int sT = 0; while ((1 << sT) < T) sT++;
    const int Mc = 4 * T;
    const int NSC = T >> 5;

    char* p = (char*)d_ws;
    __bf16* wb = (__bf16*)p; p += 25165824ull;          // 6 weights bf16, 2M elems each
    __bf16* xn = (__bf16*)p; p += (size_t)Mc * 1024 * 2;
    __bf16* zf = (__bf16*)p; p += (size_t)Mc * 2048 * 2;
    __bf16* zi = (__bf16*)p; p += (size_t)Mc * 2048 * 2;
    __bf16* x1 = (__bf16*)p; p += (size_t)Mc * 1024 * 2;
    float* Ach = (float*)p;  p += (size_t)4 * NSC * 2048 * 4;
    float* Bch = (float*)p;  p += (size_t)4 * NSC * 2048 * 4;
    float* hst = (float*)p;  p += (size_t)4 * NSC * 2048 * 4;
    float* state = (float*)p;

    __bf16* wb_f  = wb;
    __bf16* wb_i  = wb + 2097152;
    __bf16* wb_fc = wb + 2 * 2097152;
    __bf16* wb_fa = wb + 3 * 2097152;
    __bf16* wb_h  = wb + 4 * 2097152;
    __bf16* wb_o  = wb + 5 * 2097152;

    cvt_w<<<dim3(1024, 6), 256, 0, stream>>>(w_forget, w_input, w_fc, w_fc_act, w_hout, w_fout, wb);

    for (int c = 0; c < NC; c++) {
        const int t0 = c * T;
        // --- QGRU sub-block ---
        rmsnorm_f32in<<<Mc, 256, 0, stream>>>(x, g_norm1, xn, sT, t0);
        // zf <- r = decay*sigmoid(xn@Wf^T+b)   (RD=4, activation fused in epilogue)
        gemm_bt<4><<<dim3(16, Mc / 128), 256, 0, stream>>>(xn, wb_f, b_forget, nullptr, zf, 1024, 2048, sT, t0);
        // zi <- th = tanh(xn@Wi^T+b)           (RD=5)
        gemm_bt<5><<<dim3(16, Mc / 128), 256, 0, stream>>>(xn, wb_i, b_input,  nullptr, zi, 1024, 2048, sT, t0);
        scan_pass1<<<dim3(NSC, 4), 256, 0, stream>>>(zf, zi, Ach, Bch, T);
        scan_pass2<<<32, 256, 0, stream>>>(Ach, Bch, hst, hidden, state, hlast, NSC,
                                           (c == 0) ? 1 : 0, (c == NC - 1) ? 1 : 0);
        scan_pass3<<<dim3(NSC, 4), 256, 0, stream>>>(zf, zi, hst, T);
        gemm_bt<1><<<dim3(8, Mc / 128), 256, 0, stream>>>(zf, wb_h, b_hout, x, x1, 2048, 1024, sT, t0);
        // --- FFN SwiGLU sub-block ---
        rmsnorm_b16in<<<Mc, 256, 0, stream>>>(x1, g_norm2, xn);
        gemm_bt<0><<<dim3(16, Mc / 128), 256, 0, stream>>>(xn, wb_fc, b_fc,     nullptr, zf, 1024, 2048, sT, t0);
        // zf <- zf * silu(xn@Wfa^T+b)          (RD=3, SwiGLU fused; swiglu kernel eliminated)
        gemm_bt<3><<<dim3(16, Mc / 128), 256, 0, stream>>>(xn, wb_fa, b_fc_act, zf, zf, 1024, 2048, sT, t0);
        gemm_bt<2><<<dim3(8, Mc / 128), 256, 0, stream>>>(zf, wb_o, b_fout, x1, out, 2048, 1024, sT, t0);
    }
}

// Round 3
// 841.961 us; speedup vs baseline: 1.3957x; 1.3239x over previous
//
#include <hip/hip_runtime.h>
#include <hip/hip_bf16.h>

typedef __bf16 bf16x8 __attribute__((ext_vector_type(8)));
typedef __bf16 bf16x4 __attribute__((ext_vector_type(4)));
typedef float floatx4 __attribute__((ext_vector_type(4)));

#define LFULL 4096

// async global->LDS, 16B per lane. LDS dest must be wave-uniform base + lane*16.
__device__ __forceinline__ void gll16(const __bf16* g, __bf16* l) {
    __builtin_amdgcn_global_load_lds(
        (const __attribute__((address_space(1))) void*)g,
        (__attribute__((address_space(3))) void*)l, 16, 0, 0);
}

// C[Mc,N] = A[Mc,K](bf16) @ B[N,K](bf16)^T + bias(fp32)
//   RD=0: C -> bf16 compact chunk buffer
//   RD=1: C -> bf16 compact, R = fp32 global residual (token-slabbed rows)
//   RD=2: C -> fp32 global (token-slabbed rows), R = bf16 compact residual
//   RD=3: C -> bf16 compact: Rp[m,n] * silu(acc+bias)   (fused SwiGLU)
//   RD=4: C -> bf16 compact: decay(n) * sigmoid(acc+bias)  (QGRU remember gate)
//   RD=5: C -> bf16 compact: tanh(acc+bias)                (QGRU input)
// Compact chunk row m maps to global row (m>>sT)*LFULL + t0 + (m&(T-1)).
//
// 256x256 tile, 512 thr (8 waves, 2Mx4N, 128x64 out/wave), BK=32.
// 4 LDS buffers (128 KiB), 3-deep prefetch, counted s_waitcnt vmcnt(8) + raw
// s_barrier (never vmcnt(0) in steady state). LDS bank-swizzle: 16B slot
// s = q ^ ((row>>1)&3), applied on the GLOBAL source (gll16 dest is linear)
// and on the ds_read offset -> 2-way max bank aliasing (free).
template <int RD>
__global__ __launch_bounds__(512, 2) void gemm_bt(
    const __bf16* __restrict__ A, const __bf16* __restrict__ Bw,
    const float* __restrict__ bias, const void* __restrict__ Rp,
    void* __restrict__ Cp, int K, int N, int sT, int t0)
{
    __shared__ __align__(16) __bf16 As[4][256][32];   // 64 KB
    __shared__ __align__(16) __bf16 Bs[4][256][32];   // 64 KB

    const int tid  = threadIdx.x;

    // XCD-bijective chunked swizzle (nwg % 8 == 0 for all our launches)
    const int nwg = gridDim.x * gridDim.y;
    int bid = blockIdx.y * gridDim.x + blockIdx.x;
    bid = (bid & 7) * (nwg >> 3) + (bid >> 3);
    const int m0 = (bid / gridDim.x) * 256;
    const int n0 = (bid % gridDim.x) * 256;

    const int wave = tid >> 6;
    const int lane = tid & 63;
    const int wm   = (wave & 1) * 128;        // m-half of tile
    const int wn   = (wave >> 1) * 64;        // n-quarter of tile
    const int q    = lane >> 4;
    const int ml   = lane & 15;
    const int ks   = (q ^ ((ml >> 1) & 3)) * 8;   // swizzled 16B slot for ds_read

    // staging: thread t stages LDS rows (t>>2) and 128+(t>>2), 16B slot (t&3).
    // Under the swizzle, slot s at row r holds global chunk c = s ^ ((r>>1)&3);
    // (r>>1)&3 == (t>>3)&3 for both halves.
    const int t8 = tid * 8;                       // LDS elem offset of chunk 1
    const int rA = tid >> 2;
    const int cg = ((tid & 3) ^ ((tid >> 3) & 3)) * 8;  // global k-elem offset of chunk
    const __bf16* gA1 = A  + (size_t)(m0 + rA) * K + cg;
    const __bf16* gA2 = A  + (size_t)(m0 + 128 + rA) * K + cg;
    const __bf16* gB1 = Bw + (size_t)(n0 + rA) * K + cg;
    const __bf16* gB2 = Bw + (size_t)(n0 + 128 + rA) * K + cg;

    floatx4 acc[8][4] = {};
    int sb = 0;  // stage counter (K-tile index of next stage)

#define STAGE() do { \
        __bf16* la = (__bf16*)As[sb & 3]; \
        __bf16* lb = (__bf16*)Bs[sb & 3]; \
        gll16(gA1, la + t8); \
        gll16(gA2, la + 4096 + t8); \
        gll16(gB1, lb + t8); \
        gll16(gB2, lb + 4096 + t8); \
        gA1 += 32; gA2 += 32; gB1 += 32; gB2 += 32; ++sb; \
    } while (0)

#define COMPUTE(CB) do { \
        const __bf16* Ab = &As[CB][0][0]; \
        const __bf16* Bb = &Bs[CB][0][0]; \
        bf16x8 af[8], bfr[4]; \
        _Pragma("unroll") \
        for (int i = 0; i < 8; i++) \
            af[i] = *(const bf16x8*)(Ab + (wm + i * 16 + ml) * 32 + ks); \
        _Pragma("unroll") \
        for (int j = 0; j < 4; j++) \
            bfr[j] = *(const bf16x8*)(Bb + (wn + j * 16 + ml) * 32 + ks); \
        __builtin_amdgcn_s_setprio(1); \
        _Pragma("unroll") \
        for (int i = 0; i < 8; i++) \
            _Pragma("unroll") \
            for (int j = 0; j < 4; j++) \
                acc[i][j] = __builtin_amdgcn_mfma_f32_16x16x32_bf16(af[i], bfr[j], acc[i][j], 0, 0, 0); \
        __builtin_amdgcn_s_setprio(0); \
    } while (0)

    const int NT = K >> 5;                 // 32 or 64 K-tiles
    STAGE(); STAGE(); STAGE();             // prologue: tiles 0,1,2 in flight (12 loads)
    asm volatile("s_waitcnt vmcnt(8)" ::: "memory");   // tile 0 landed
    __builtin_amdgcn_s_barrier();
    __builtin_amdgcn_sched_barrier(0);

    for (int kt = 0; kt < NT; ++kt) {
        if (kt + 3 < NT) STAGE();          // prefetch 3 ahead into free buffer
        COMPUTE(kt & 3);
        const int rem = NT - 1 - kt;
        // wait only until NEXT tile's 4 loads are home; keep the rest in flight
        if (rem >= 3)      { asm volatile("s_waitcnt vmcnt(8)" ::: "memory"); }
        else if (rem == 2) { asm volatile("s_waitcnt vmcnt(4)" ::: "memory"); }
        else if (rem == 1) { asm volatile("s_waitcnt vmcnt(0)" ::: "memory"); }
        if (rem > 0) {
            __builtin_amdgcn_s_barrier();
            __builtin_amdgcn_sched_barrier(0);
        }
    }

#undef STAGE
#undef COMPUTE

    const int Tmask = (1 << sT) - 1;
#pragma unroll
    for (int i = 0; i < 8; i++) {
#pragma unroll
        for (int j = 0; j < 4; j++) {
            const int n = n0 + wn + j * 16 + ml;
            const float bv = bias[n];
            const float dec = (float)n * (1.0f / 2047.0f);
#pragma unroll
            for (int r = 0; r < 4; r++) {
                const int m = m0 + wm + i * 16 + q * 4 + r;
                float v = acc[i][j][r] + bv;
                if (RD == 1) {
                    const int gm = ((m >> sT) * LFULL) + t0 + (m & Tmask);
                    v += ((const float*)Rp)[(size_t)gm * N + n];
                    ((__bf16*)Cp)[(size_t)m * N + n] = (__bf16)v;
                } else if (RD == 2) {
                    v += (float)((const __bf16*)Rp)[(size_t)m * N + n];
                    const int gm = ((m >> sT) * LFULL) + t0 + (m & Tmask);
                    ((float*)Cp)[(size_t)gm * N + n] = v;
                } else if (RD == 3) {
                    // fused SwiGLU: z1 * silu(z2), z2 = acc+bias (fp32)
                    const float sl = v / (1.f + __expf(-v));
                    const float z1 = (float)((const __bf16*)Rp)[(size_t)m * N + n];
                    ((__bf16*)Cp)[(size_t)m * N + n] = (__bf16)(z1 * sl);
                } else if (RD == 4) {
                    // remember gate r = decay(n)*sigmoid(z); __expf(-v)->inf => r->0 (safe)
                    const float rr = dec / (1.f + __expf(-v));
                    ((__bf16*)Cp)[(size_t)m * N + n] = (__bf16)rr;
                } else if (RD == 5) {
                    // tanh(z); saturates safely at +-1 for large |v|
                    const float e = __expf(2.f * v);
                    const float th = 1.f - 2.f / (e + 1.f);
                    ((__bf16*)Cp)[(size_t)m * N + n] = (__bf16)th;
                } else {
                    ((__bf16*)Cp)[(size_t)m * N + n] = (__bf16)v;
                }
            }
        }
    }
}

// fp32 -> bf16 weight conversion; blockIdx.y selects one of 6 weights (2M elems each).
__global__ __launch_bounds__(256) void cvt_w(
    const float* __restrict__ s0, const float* __restrict__ s1,
    const float* __restrict__ s2, const float* __restrict__ s3,
    const float* __restrict__ s4, const float* __restrict__ s5,
    __bf16* __restrict__ dst)
{
    const float* srcs[6] = {s0, s1, s2, s3, s4, s5};
    const float* s = srcs[blockIdx.y];
    __bf16* d = dst + (size_t)blockIdx.y * 2097152;
    const int i = (blockIdx.x * 256 + threadIdx.x) * 8;
    float4 f0 = *(const float4*)(s + i);
    float4 f1 = *(const float4*)(s + i + 4);
    bf16x8 o;
    o[0] = (__bf16)f0.x; o[1] = (__bf16)f0.y; o[2] = (__bf16)f0.z; o[3] = (__bf16)f0.w;
    o[4] = (__bf16)f1.x; o[5] = (__bf16)f1.y; o[6] = (__bf16)f1.z; o[7] = (__bf16)f1.w;
    *(bf16x8*)(d + i) = o;
}

// RMSNorm over D=1024, fp32 token-slabbed input -> bf16 compact.
__global__ __launch_bounds__(256) void rmsnorm_f32in(
    const float* __restrict__ x, const float* __restrict__ g,
    __bf16* __restrict__ o, int sT, int t0)
{
    const int r = blockIdx.x;
    const int grow = ((r >> sT) * LFULL) + t0 + (r & ((1 << sT) - 1));
    const float* xr = x + (size_t)grow * 1024;
    const int tid = threadIdx.x;

    float4 v = *(const float4*)(xr + tid * 4);
    float vv[4] = {v.x, v.y, v.z, v.w};
    float ss = vv[0] * vv[0] + vv[1] * vv[1] + vv[2] * vv[2] + vv[3] * vv[3];
#pragma unroll
    for (int off = 32; off > 0; off >>= 1) ss += __shfl_down(ss, off);

    __shared__ float red[4];
    if ((tid & 63) == 0) red[tid >> 6] = ss;
    __syncthreads();
    const float tot = red[0] + red[1] + red[2] + red[3];
    const float scale = rsqrtf(tot * (1.0f / 1024.0f) + 1e-6f);

    float4 g4 = *(const float4*)(g + tid * 4);
    float gg[4] = {g4.x, g4.y, g4.z, g4.w};
    bf16x4 ov;
#pragma unroll
    for (int e = 0; e < 4; e++) ov[e] = (__bf16)(vv[e] * scale * gg[e]);
    *(bf16x4*)(o + (size_t)r * 1024 + tid * 4) = ov;
}

// RMSNorm over D=1024, bf16 compact -> bf16 compact.
__global__ __launch_bounds__(256) void rmsnorm_b16in(
    const __bf16* __restrict__ x, const float* __restrict__ g,
    __bf16* __restrict__ o)
{
    const int r = blockIdx.x;
    const __bf16* xr = x + (size_t)r * 1024;
    const int tid = threadIdx.x;

    bf16x4 v = *(const bf16x4*)(xr + tid * 4);
    float vv[4];
#pragma unroll
    for (int e = 0; e < 4; e++) vv[e] = (float)v[e];
    float ss = vv[0] * vv[0] + vv[1] * vv[1] + vv[2] * vv[2] + vv[3] * vv[3];
#pragma unroll
    for (int off = 32; off > 0; off >>= 1) ss += __shfl_down(ss, off);

    __shared__ float red[4];
    if ((tid & 63) == 0) red[tid >> 6] = ss;
    __syncthreads();
    const float tot = red[0] + red[1] + red[2] + red[3];
    const float scale = rsqrtf(tot * (1.0f / 1024.0f) + 1e-6f);

    float4 g4 = *(const float4*)(g + tid * 4);
    float gg[4] = {g4.x, g4.y, g4.z, g4.w};
    bf16x4 ov;
#pragma unroll
    for (int e = 0; e < 4; e++) ov[e] = (__bf16)(vv[e] * scale * gg[e]);
    *(bf16x4*)(o + (size_t)r * 1024 + tid * 4) = ov;
}

// ---- parallel linear-recurrence scan: h[t] = (1-r)h[t-1] + r*th ----
// r, th are precomputed in the GEMM epilogues (RD=4 / RD=5) and stored bf16.
// Pass 1: 32-step sub-chunk summaries (A = prod a, B = scan from 0), fp32.
// Vectorized: 8 h-channels per thread (bf16x8 = 16 B/lane); 256 thr cover all 2048 h.
__global__ __launch_bounds__(256) void scan_pass1(
    const __bf16* __restrict__ rr, const __bf16* __restrict__ th,
    float* __restrict__ Ach, float* __restrict__ Bch, int T)
{
    const int h0 = threadIdx.x * 8;
    const int s = blockIdx.x;                      // sub-chunk
    const int b = blockIdx.y;
    const int NSC = T >> 5;
    size_t p = ((size_t)b * T + s * 32) * 2048 + h0;
    float Aa[8], Bv[8];
#pragma unroll
    for (int e = 0; e < 8; e++) { Aa[e] = 1.f; Bv[e] = 0.f; }
    for (int t = 0; t < 32; t++, p += 2048) {
        bf16x8 rv = *(const bf16x8*)(rr + p);
        bf16x8 tv = *(const bf16x8*)(th + p);
#pragma unroll
        for (int e = 0; e < 8; e++) {
            const float r = (float)rv[e];
            const float a = 1.f - r;
            Aa[e] *= a;
            Bv[e] = a * Bv[e] + r * (float)tv[e];
        }
    }
    const size_t qq = (size_t)(b * NSC + s) * 2048 + h0;
#pragma unroll
    for (int e = 0; e < 8; e++) { Ach[qq + e] = Aa[e]; Bch[qq + e] = Bv[e]; }
}

// Pass 2: sequential composition over sub-chunk summaries; emits start-state per sub-chunk.
__global__ __launch_bounds__(256) void scan_pass2(
    const float* __restrict__ Ach, const float* __restrict__ Bch,
    float* __restrict__ hst, const float* __restrict__ hidden,
    float* __restrict__ state, float* __restrict__ hlast,
    int NSC, int first, int last)
{
    const int idx = blockIdx.x * 256 + threadIdx.x;  // 0..8191 = (b,h)
    const int b = idx >> 11;
    const int h = idx & 2047;
    float hs = first ? hidden[idx] : state[idx];
    size_t qq = (size_t)b * NSC * 2048 + h;
#pragma unroll 4
    for (int s = 0; s < NSC; s++, qq += 2048) {
        hst[qq] = hs;
        hs = Ach[qq] * hs + Bch[qq];
    }
    state[idx] = hs;
    if (last) hlast[idx] = hs;
}

// Pass 3: replay each sub-chunk from its fp32 start state; write h (bf16) over r in place.
// Vectorized: 8 h-channels per thread.
__global__ __launch_bounds__(256) void scan_pass3(
    __bf16* __restrict__ rio, const __bf16* __restrict__ th,
    const float* __restrict__ hst, int T)
{
    const int h0 = threadIdx.x * 8;
    const int s = blockIdx.x;
    const int b = blockIdx.y;
    const int NSC = T >> 5;
    float hp[8];
    const size_t qq = (size_t)(b * NSC + s) * 2048 + h0;
#pragma unroll
    for (int e = 0; e < 8; e++) hp[e] = hst[qq + e];
    size_t p = ((size_t)b * T + s * 32) * 2048 + h0;
    for (int t = 0; t < 32; t++, p += 2048) {
        bf16x8 rv = *(const bf16x8*)(rio + p);
        bf16x8 tv = *(const bf16x8*)(th + p);
        bf16x8 ov;
#pragma unroll
        for (int e = 0; e < 8; e++) {
            const float r = (float)rv[e];
            hp[e] = (1.f - r) * hp[e] + r * (float)tv[e];
            ov[e] = (__bf16)hp[e];
        }
        *(bf16x8*)(rio + p) = ov;
    }
}

extern "C" void kernel_launch(void* const* d_in, const int* in_sizes, int n_in,
                              void* d_out, int out_size, void* d_ws, size_t ws_size,
                              hipStream_t stream)
{
    const float* x        = (const float*)d_in[0];
    const float* hidden   = (const float*)d_in[1];
    const float* w_forget = (const float*)d_in[2];
    const float* b_forget = (const float*)d_in[3];
    const float* w_input  = (const float*)d_in[4];
    const float* b_input  = (const float*)d_in[5];
    const float* w_hout   = (const float*)d_in[6];
    const float* b_hout   = (const float*)d_in[7];
    const float* w_fc     = (const float*)d_in[8];
    const float* b_fc     = (const float*)d_in[9];
    const float* w_fc_act = (const float*)d_in[10];
    const float* b_fc_act = (const float*)d_in[11];
    const float* w_fout   = (const float*)d_in[12];
    const float* b_fout   = (const float*)d_in[13];
    const float* g_norm1  = (const float*)d_in[14];
    const float* g_norm2  = (const float*)d_in[15];

    float* out   = (float*)d_out;
    float* hlast = out + (size_t)16384 * 1024;

    // workspace need(T): wb 24MB + chunk activations + scan summaries + state
    int T = 4096;
    for (;;) {
        size_t need = 25165824ull + (size_t)4 * T * 12288 + 3ull * 4 * (T / 32) * 2048 * 4 + 65536;
        if (need <= ws_size || T == 256) break;
        T >>= 1;
    }
    const int NC = 4096 / T;
    int sT = 0; while ((1 << sT) < T) sT++;
    const int Mc = 4 * T;
    const int NSC = T >> 5;

    char* p = (char*)d_ws;
    __bf16* wb = (__bf16*)p; p += 25165824ull;          // 6 weights bf16, 2M elems each
    __bf16* xn = (__bf16*)p; p += (size_t)Mc * 1024 * 2;
    __bf16* zf = (__bf16*)p; p += (size_t)Mc * 2048 * 2;
    __bf16* zi = (__bf16*)p; p += (size_t)Mc * 2048 * 2;
    __bf16* x1 = (__bf16*)p; p += (size_t)Mc * 1024 * 2;
    float* Ach = (float*)p;  p += (size_t)4 * NSC * 2048 * 4;
    float* Bch = (float*)p;  p += (size_t)4 * NSC * 2048 * 4;
    float* hst = (float*)p;  p += (size_t)4 * NSC * 2048 * 4;
    float* state = (float*)p;

    __bf16* wb_f  = wb;
    __bf16* wb_i  = wb + 2097152;
    __bf16* wb_fc = wb + 2 * 2097152;
    __bf16* wb_fa = wb + 3 * 2097152;
    __bf16* wb_h  = wb + 4 * 2097152;
    __bf16* wb_o  = wb + 5 * 2097152;

    cvt_w<<<dim3(1024, 6), 256, 0, stream>>>(w_forget, w_input, w_fc, w_fc_act, w_hout, w_fout, wb);

    for (int c = 0; c < NC; c++) {
        const int t0 = c * T;
        // --- QGRU sub-block ---
        rmsnorm_f32in<<<Mc, 256, 0, stream>>>(x, g_norm1, xn, sT, t0);
        // zf <- r = decay*sigmoid(xn@Wf^T+b)   (RD=4, activation fused in epilogue)
        gemm_bt<4><<<dim3(8, Mc / 256), 512, 0, stream>>>(xn, wb_f, b_forget, nullptr, zf, 1024, 2048, sT, t0);
        // zi <- th = tanh(xn@Wi^T+b)           (RD=5)
        gemm_bt<5><<<dim3(8, Mc / 256), 512, 0, stream>>>(xn, wb_i, b_input,  nullptr, zi, 1024, 2048, sT, t0);
        scan_pass1<<<dim3(NSC, 4), 256, 0, stream>>>(zf, zi, Ach, Bch, T);
        scan_pass2<<<32, 256, 0, stream>>>(Ach, Bch, hst, hidden, state, hlast, NSC,
                                           (c == 0) ? 1 : 0, (c == NC - 1) ? 1 : 0);
        scan_pass3<<<dim3(NSC, 4), 256, 0, stream>>>(zf, zi, hst, T);
        gemm_bt<1><<<dim3(4, Mc / 256), 512, 0, stream>>>(zf, wb_h, b_hout, x, x1, 2048, 1024, sT, t0);
        // --- FFN SwiGLU sub-block ---
        rmsnorm_b16in<<<Mc, 256, 0, stream>>>(x1, g_norm2, xn);
        gemm_bt<0><<<dim3(8, Mc / 256), 512, 0, stream>>>(xn, wb_fc, b_fc,     nullptr, zf, 1024, 2048, sT, t0);
        // zf <- zf * silu(xn@Wfa^T+b)          (RD=3, SwiGLU fused)
        gemm_bt<3><<<dim3(8, Mc / 256), 512, 0, stream>>>(xn, wb_fa, b_fc_act, zf, zf, 1024, 2048, sT, t0);
        gemm_bt<2><<<dim3(4, Mc / 256), 512, 0, stream>>>(zf, wb_o, b_fout, x1, out, 2048, 1024, sT, t0);
    }
}

// Round 4
// 752.095 us; speedup vs baseline: 1.5624x; 1.1195x over previous
//
#include <hip/hip_runtime.h>
#include <hip/hip_bf16.h>

typedef __bf16 bf16x8 __attribute__((ext_vector_type(8)));
typedef __bf16 bf16x4 __attribute__((ext_vector_type(4)));
typedef float floatx4 __attribute__((ext_vector_type(4)));

#define LFULL 4096

// async global->LDS, 16B per lane. LDS dest must be wave-uniform base + lane*16.
__device__ __forceinline__ void gll16(const __bf16* g, __bf16* l) {
    __builtin_amdgcn_global_load_lds(
        (const __attribute__((address_space(1))) void*)g,
        (__attribute__((address_space(3))) void*)l, 16, 0, 0);
}

// C[Mc,N] = A[Mc,K](bf16) @ B[N,K](bf16)^T + bias(fp32)
//   RD=0: C -> bf16 compact chunk buffer
//   RD=1: C -> bf16 compact, R = fp32 global residual (token-slabbed rows)
//   RD=2: C -> fp32 global (token-slabbed rows), R = bf16 compact residual
//   RD=3: C -> bf16 compact: Rp[m,n] * silu(acc+bias)   (fused SwiGLU)
//   RD=4: C -> bf16 compact: decay(n) * sigmoid(acc+bias)  (QGRU remember gate)
//   RD=5: C -> bf16 compact: tanh(acc+bias)                (QGRU input)
// Compact chunk row m maps to global row (m>>sT)*LFULL + t0 + (m&(T-1)).
//
// 256x256 tile, 512 thr (8 waves, 2Mx4N, 128x64 out/wave), BK=32.
// 4 LDS buffers (128 KiB), 3-deep prefetch, counted s_waitcnt vmcnt(8).
// Each K-tile split into TWO phases of 16 MFMA (8-phase-style rhythm):
//   {ds_read subtile || stage 2 gll16 -> barrier -> lgkmcnt(0) ->
//    setprio(1) 16 MFMA setprio(0) -> barrier}
// so ds_read latency of phase p hides under the barrier/MFMA of the other
// waves, and the 2 resident waves/SIMD get role-split (setprio pays).
template <int RD>
__global__ __launch_bounds__(512, 2) void gemm_bt(
    const __bf16* __restrict__ A, const __bf16* __restrict__ Bw,
    const float* __restrict__ bias, const void* __restrict__ Rp,
    void* __restrict__ Cp, int K, int N, int sT, int t0)
{
    __shared__ __align__(16) __bf16 As[4][256][32];   // 64 KB
    __shared__ __align__(16) __bf16 Bs[4][256][32];   // 64 KB

    const int tid  = threadIdx.x;

    // XCD-bijective chunked swizzle (nwg % 8 == 0 for all our launches)
    const int nwg = gridDim.x * gridDim.y;
    int bid = blockIdx.y * gridDim.x + blockIdx.x;
    bid = (bid & 7) * (nwg >> 3) + (bid >> 3);
    const int m0 = (bid / gridDim.x) * 256;
    const int n0 = (bid % gridDim.x) * 256;

    const int wave = tid >> 6;
    const int lane = tid & 63;
    const int wm   = (wave & 1) * 128;        // m-half of tile
    const int wn   = (wave >> 1) * 64;        // n-quarter of tile
    const int q    = lane >> 4;
    const int ml   = lane & 15;
    const int ks   = (q ^ ((ml >> 1) & 3)) * 8;   // swizzled 16B slot for ds_read

    // staging: thread t stages LDS rows (t>>2) and 128+(t>>2), 16B slot (t&3).
    // Under the swizzle, slot s at row r holds global chunk c = s ^ ((r>>1)&3).
    const int t8 = tid * 8;                       // LDS elem offset of chunk 1
    const int rA = tid >> 2;
    const int cg = ((tid & 3) ^ ((tid >> 3) & 3)) * 8;  // global k-elem offset of chunk
    const __bf16* gA1 = A  + (size_t)(m0 + rA) * K + cg;
    const __bf16* gA2 = A  + (size_t)(m0 + 128 + rA) * K + cg;
    const __bf16* gB1 = Bw + (size_t)(n0 + rA) * K + cg;
    const __bf16* gB2 = Bw + (size_t)(n0 + 128 + rA) * K + cg;

    floatx4 acc[8][4] = {};
    int sb = 0;  // stage counter (K-tile index of next stage)

#define STAGE_FULL() do { \
        __bf16* la = (__bf16*)As[sb & 3]; \
        __bf16* lb = (__bf16*)Bs[sb & 3]; \
        gll16(gA1, la + t8); \
        gll16(gA2, la + 4096 + t8); \
        gll16(gB1, lb + t8); \
        gll16(gB2, lb + 4096 + t8); \
        gA1 += 32; gA2 += 32; gB1 += 32; gB2 += 32; ++sb; \
    } while (0)

#define STAGE_A() do { \
        __bf16* la = (__bf16*)As[sb & 3]; \
        gll16(gA1, la + t8); \
        gll16(gA2, la + 4096 + t8); \
        gA1 += 32; gA2 += 32; \
    } while (0)

#define STAGE_B() do { \
        __bf16* lb = (__bf16*)Bs[sb & 3]; \
        gll16(gB1, lb + t8); \
        gll16(gB2, lb + 4096 + t8); \
        gB1 += 32; gB2 += 32; ++sb; \
    } while (0)

    const int NT = K >> 5;                 // 32 or 64 K-tiles
    STAGE_FULL(); STAGE_FULL(); STAGE_FULL();   // tiles 0,1,2 in flight (12 loads)
    asm volatile("s_waitcnt vmcnt(8)" ::: "memory");   // tile 0 landed
    __builtin_amdgcn_s_barrier();

    for (int kt = 0; kt < NT; ++kt) {
        const int CB = kt & 3;
        const __bf16* Ab = &As[CB][0][0];
        const __bf16* Bb = &Bs[CB][0][0];
        bf16x8 af[4], bfr[4];
        const bool pre = (kt + 3 < NT);

        // ---- phase 0: m-rows [wm, wm+64) x all n, full K=32 ----
#pragma unroll
        for (int i = 0; i < 4; i++)
            af[i] = *(const bf16x8*)(Ab + (wm + i * 16 + ml) * 32 + ks);
#pragma unroll
        for (int j = 0; j < 4; j++)
            bfr[j] = *(const bf16x8*)(Bb + (wn + j * 16 + ml) * 32 + ks);
        if (pre) STAGE_A();
        __builtin_amdgcn_s_barrier();
        asm volatile("s_waitcnt lgkmcnt(0)" ::: "memory");
        __builtin_amdgcn_sched_barrier(0);
        __builtin_amdgcn_s_setprio(1);
#pragma unroll
        for (int i = 0; i < 4; i++)
#pragma unroll
            for (int j = 0; j < 4; j++)
                acc[i][j] = __builtin_amdgcn_mfma_f32_16x16x32_bf16(af[i], bfr[j], acc[i][j], 0, 0, 0);
        __builtin_amdgcn_s_setprio(0);
        __builtin_amdgcn_s_barrier();

        // ---- phase 1: m-rows [wm+64, wm+128) x all n (bfr stays live) ----
#pragma unroll
        for (int i = 0; i < 4; i++)
            af[i] = *(const bf16x8*)(Ab + (wm + 64 + i * 16 + ml) * 32 + ks);
        if (pre) STAGE_B();
        __builtin_amdgcn_s_barrier();
        asm volatile("s_waitcnt lgkmcnt(0)" ::: "memory");
        __builtin_amdgcn_sched_barrier(0);
        __builtin_amdgcn_s_setprio(1);
#pragma unroll
        for (int i = 0; i < 4; i++)
#pragma unroll
            for (int j = 0; j < 4; j++)
                acc[4 + i][j] = __builtin_amdgcn_mfma_f32_16x16x32_bf16(af[i], bfr[j], acc[4 + i][j], 0, 0, 0);
        __builtin_amdgcn_s_setprio(0);
        // tile-boundary wait: next tile's loads home, rest stay in flight
        const int rem = NT - 1 - kt;
        if (rem >= 3)      { asm volatile("s_waitcnt vmcnt(8)" ::: "memory"); }
        else if (rem == 2) { asm volatile("s_waitcnt vmcnt(4)" ::: "memory"); }
        else if (rem == 1) { asm volatile("s_waitcnt vmcnt(0)" ::: "memory"); }
        __builtin_amdgcn_s_barrier();
    }

#undef STAGE_FULL
#undef STAGE_A
#undef STAGE_B

    const int Tmask = (1 << sT) - 1;
#pragma unroll
    for (int i = 0; i < 8; i++) {
#pragma unroll
        for (int j = 0; j < 4; j++) {
            const int n = n0 + wn + j * 16 + ml;
            const float bv = bias[n];
            const float dec = (float)n * (1.0f / 2047.0f);
#pragma unroll
            for (int r = 0; r < 4; r++) {
                const int m = m0 + wm + i * 16 + q * 4 + r;
                float v = acc[i][j][r] + bv;
                if (RD == 1) {
                    const int gm = ((m >> sT) * LFULL) + t0 + (m & Tmask);
                    v += ((const float*)Rp)[(size_t)gm * N + n];
                    ((__bf16*)Cp)[(size_t)m * N + n] = (__bf16)v;
                } else if (RD == 2) {
                    v += (float)((const __bf16*)Rp)[(size_t)m * N + n];
                    const int gm = ((m >> sT) * LFULL) + t0 + (m & Tmask);
                    ((float*)Cp)[(size_t)gm * N + n] = v;
                } else if (RD == 3) {
                    // fused SwiGLU: z1 * silu(z2), z2 = acc+bias (fp32)
                    const float sl = v / (1.f + __expf(-v));
                    const float z1 = (float)((const __bf16*)Rp)[(size_t)m * N + n];
                    ((__bf16*)Cp)[(size_t)m * N + n] = (__bf16)(z1 * sl);
                } else if (RD == 4) {
                    // remember gate r = decay(n)*sigmoid(z); __expf(-v)->inf => r->0 (safe)
                    const float rr = dec / (1.f + __expf(-v));
                    ((__bf16*)Cp)[(size_t)m * N + n] = (__bf16)rr;
                } else if (RD == 5) {
                    // tanh(z); saturates safely at +-1 for large |v|
                    const float e = __expf(2.f * v);
                    const float th = 1.f - 2.f / (e + 1.f);
                    ((__bf16*)Cp)[(size_t)m * N + n] = (__bf16)th;
                } else {
                    ((__bf16*)Cp)[(size_t)m * N + n] = (__bf16)v;
                }
            }
        }
    }
}

// fp32 -> bf16 weight conversion; blockIdx.y selects one of 6 weights (2M elems each).
__global__ __launch_bounds__(256) void cvt_w(
    const float* __restrict__ s0, const float* __restrict__ s1,
    const float* __restrict__ s2, const float* __restrict__ s3,
    const float* __restrict__ s4, const float* __restrict__ s5,
    __bf16* __restrict__ dst)
{
    const float* srcs[6] = {s0, s1, s2, s3, s4, s5};
    const float* s = srcs[blockIdx.y];
    __bf16* d = dst + (size_t)blockIdx.y * 2097152;
    const int i = (blockIdx.x * 256 + threadIdx.x) * 8;
    float4 f0 = *(const float4*)(s + i);
    float4 f1 = *(const float4*)(s + i + 4);
    bf16x8 o;
    o[0] = (__bf16)f0.x; o[1] = (__bf16)f0.y; o[2] = (__bf16)f0.z; o[3] = (__bf16)f0.w;
    o[4] = (__bf16)f1.x; o[5] = (__bf16)f1.y; o[6] = (__bf16)f1.z; o[7] = (__bf16)f1.w;
    *(bf16x8*)(d + i) = o;
}

// RMSNorm over D=1024, fp32 token-slabbed input -> bf16 compact.
__global__ __launch_bounds__(256) void rmsnorm_f32in(
    const float* __restrict__ x, const float* __restrict__ g,
    __bf16* __restrict__ o, int sT, int t0)
{
    const int r = blockIdx.x;
    const int grow = ((r >> sT) * LFULL) + t0 + (r & ((1 << sT) - 1));
    const float* xr = x + (size_t)grow * 1024;
    const int tid = threadIdx.x;

    float4 v = *(const float4*)(xr + tid * 4);
    float vv[4] = {v.x, v.y, v.z, v.w};
    float ss = vv[0] * vv[0] + vv[1] * vv[1] + vv[2] * vv[2] + vv[3] * vv[3];
#pragma unroll
    for (int off = 32; off > 0; off >>= 1) ss += __shfl_down(ss, off);

    __shared__ float red[4];
    if ((tid & 63) == 0) red[tid >> 6] = ss;
    __syncthreads();
    const float tot = red[0] + red[1] + red[2] + red[3];
    const float scale = rsqrtf(tot * (1.0f / 1024.0f) + 1e-6f);

    float4 g4 = *(const float4*)(g + tid * 4);
    float gg[4] = {g4.x, g4.y, g4.z, g4.w};
    bf16x4 ov;
#pragma unroll
    for (int e = 0; e < 4; e++) ov[e] = (__bf16)(vv[e] * scale * gg[e]);
    *(bf16x4*)(o + (size_t)r * 1024 + tid * 4) = ov;
}

// RMSNorm over D=1024, bf16 compact -> bf16 compact.
__global__ __launch_bounds__(256) void rmsnorm_b16in(
    const __bf16* __restrict__ x, const float* __restrict__ g,
    __bf16* __restrict__ o)
{
    const int r = blockIdx.x;
    const __bf16* xr = x + (size_t)r * 1024;
    const int tid = threadIdx.x;

    bf16x4 v = *(const bf16x4*)(xr + tid * 4);
    float vv[4];
#pragma unroll
    for (int e = 0; e < 4; e++) vv[e] = (float)v[e];
    float ss = vv[0] * vv[0] + vv[1] * vv[1] + vv[2] * vv[2] + vv[3] * vv[3];
#pragma unroll
    for (int off = 32; off > 0; off >>= 1) ss += __shfl_down(ss, off);

    __shared__ float red[4];
    if ((tid & 63) == 0) red[tid >> 6] = ss;
    __syncthreads();
    const float tot = red[0] + red[1] + red[2] + red[3];
    const float scale = rsqrtf(tot * (1.0f / 1024.0f) + 1e-6f);

    float4 g4 = *(const float4*)(g + tid * 4);
    float gg[4] = {g4.x, g4.y, g4.z, g4.w};
    bf16x4 ov;
#pragma unroll
    for (int e = 0; e < 4; e++) ov[e] = (__bf16)(vv[e] * scale * gg[e]);
    *(bf16x4*)(o + (size_t)r * 1024 + tid * 4) = ov;
}

// ---- parallel linear-recurrence scan: h[t] = (1-r)h[t-1] + r*th ----
// r, th are precomputed in the GEMM epilogues (RD=4 / RD=5) and stored bf16.
// Pass 1: 32-step sub-chunk summaries (A = prod a, B = scan from 0), fp32.
// Vectorized: 8 h-channels per thread (bf16x8 = 16 B/lane); 256 thr cover all 2048 h.
__global__ __launch_bounds__(256) void scan_pass1(
    const __bf16* __restrict__ rr, const __bf16* __restrict__ th,
    float* __restrict__ Ach, float* __restrict__ Bch, int T)
{
    const int h0 = threadIdx.x * 8;
    const int s = blockIdx.x;                      // sub-chunk
    const int b = blockIdx.y;
    const int NSC = T >> 5;
    size_t p = ((size_t)b * T + s * 32) * 2048 + h0;
    float Aa[8], Bv[8];
#pragma unroll
    for (int e = 0; e < 8; e++) { Aa[e] = 1.f; Bv[e] = 0.f; }
    for (int t = 0; t < 32; t++, p += 2048) {
        bf16x8 rv = *(const bf16x8*)(rr + p);
        bf16x8 tv = *(const bf16x8*)(th + p);
#pragma unroll
        for (int e = 0; e < 8; e++) {
            const float r = (float)rv[e];
            const float a = 1.f - r;
            Aa[e] *= a;
            Bv[e] = a * Bv[e] + r * (float)tv[e];
        }
    }
    const size_t qq = (size_t)(b * NSC + s) * 2048 + h0;
#pragma unroll
    for (int e = 0; e < 8; e++) { Ach[qq + e] = Aa[e]; Bch[qq + e] = Bv[e]; }
}

// Pass 2: sequential composition over sub-chunk summaries; emits start-state per sub-chunk.
__global__ __launch_bounds__(256) void scan_pass2(
    const float* __restrict__ Ach, const float* __restrict__ Bch,
    float* __restrict__ hst, const float* __restrict__ hidden,
    float* __restrict__ state, float* __restrict__ hlast,
    int NSC, int first, int last)
{
    const int idx = blockIdx.x * 256 + threadIdx.x;  // 0..8191 = (b,h)
    const int b = idx >> 11;
    const int h = idx & 2047;
    float hs = first ? hidden[idx] : state[idx];
    size_t qq = (size_t)b * NSC * 2048 + h;
#pragma unroll 4
    for (int s = 0; s < NSC; s++, qq += 2048) {
        hst[qq] = hs;
        hs = Ach[qq] * hs + Bch[qq];
    }
    state[idx] = hs;
    if (last) hlast[idx] = hs;
}

// Pass 3: replay each sub-chunk from its fp32 start state; write h (bf16) over r in place.
// Vectorized: 8 h-channels per thread.
__global__ __launch_bounds__(256) void scan_pass3(
    __bf16* __restrict__ rio, const __bf16* __restrict__ th,
    const float* __restrict__ hst, int T)
{
    const int h0 = threadIdx.x * 8;
    const int s = blockIdx.x;
    const int b = blockIdx.y;
    const int NSC = T >> 5;
    float hp[8];
    const size_t qq = (size_t)(b * NSC + s) * 2048 + h0;
#pragma unroll
    for (int e = 0; e < 8; e++) hp[e] = hst[qq + e];
    size_t p = ((size_t)b * T + s * 32) * 2048 + h0;
    for (int t = 0; t < 32; t++, p += 2048) {
        bf16x8 rv = *(const bf16x8*)(rio + p);
        bf16x8 tv = *(const bf16x8*)(th + p);
        bf16x8 ov;
#pragma unroll
        for (int e = 0; e < 8; e++) {
            const float r = (float)rv[e];
            hp[e] = (1.f - r) * hp[e] + r * (float)tv[e];
            ov[e] = (__bf16)hp[e];
        }
        *(bf16x8*)(rio + p) = ov;
    }
}

extern "C" void kernel_launch(void* const* d_in, const int* in_sizes, int n_in,
                              void* d_out, int out_size, void* d_ws, size_t ws_size,
                              hipStream_t stream)
{
    const float* x        = (const float*)d_in[0];
    const float* hidden   = (const float*)d_in[1];
    const float* w_forget = (const float*)d_in[2];
    const float* b_forget = (const float*)d_in[3];
    const float* w_input  = (const float*)d_in[4];
    const float* b_input  = (const float*)d_in[5];
    const float* w_hout   = (const float*)d_in[6];
    const float* b_hout   = (const float*)d_in[7];
    const float* w_fc     = (const float*)d_in[8];
    const float* b_fc     = (const float*)d_in[9];
    const float* w_fc_act = (const float*)d_in[10];
    const float* b_fc_act = (const float*)d_in[11];
    const float* w_fout   = (const float*)d_in[12];
    const float* b_fout   = (const float*)d_in[13];
    const float* g_norm1  = (const float*)d_in[14];
    const float* g_norm2  = (const float*)d_in[15];

    float* out   = (float*)d_out;
    float* hlast = out + (size_t)16384 * 1024;

    // workspace need(T): wb 24MB + chunk activations + scan summaries + state
    int T = 4096;
    for (;;) {
        size_t need = 25165824ull + (size_t)4 * T * 12288 + 3ull * 4 * (T / 32) * 2048 * 4 + 65536;
        if (need <= ws_size || T == 256) break;
        T >>= 1;
    }
    const int NC = 4096 / T;
    int sT = 0; while ((1 << sT) < T) sT++;
    const int Mc = 4 * T;
    const int NSC = T >> 5;

    char* p = (char*)d_ws;
    __bf16* wb = (__bf16*)p; p += 25165824ull;          // 6 weights bf16, 2M elems each
    __bf16* xn = (__bf16*)p; p += (size_t)Mc * 1024 * 2;
    __bf16* zf = (__bf16*)p; p += (size_t)Mc * 2048 * 2;
    __bf16* zi = (__bf16*)p; p += (size_t)Mc * 2048 * 2;
    __bf16* x1 = (__bf16*)p; p += (size_t)Mc * 1024 * 2;
    float* Ach = (float*)p;  p += (size_t)4 * NSC * 2048 * 4;
    float* Bch = (float*)p;  p += (size_t)4 * NSC * 2048 * 4;
    float* hst = (float*)p;  p += (size_t)4 * NSC * 2048 * 4;
    float* state = (float*)p;

    __bf16* wb_f  = wb;
    __bf16* wb_i  = wb + 2097152;
    __bf16* wb_fc = wb + 2 * 2097152;
    __bf16* wb_fa = wb + 3 * 2097152;
    __bf16* wb_h  = wb + 4 * 2097152;
    __bf16* wb_o  = wb + 5 * 2097152;

    cvt_w<<<dim3(1024, 6), 256, 0, stream>>>(w_forget, w_input, w_fc, w_fc_act, w_hout, w_fout, wb);

    for (int c = 0; c < NC; c++) {
        const int t0 = c * T;
        // --- QGRU sub-block ---
        rmsnorm_f32in<<<Mc, 256, 0, stream>>>(x, g_norm1, xn, sT, t0);
        // zf <- r = decay*sigmoid(xn@Wf^T+b)   (RD=4, activation fused in epilogue)
        gemm_bt<4><<<dim3(8, Mc / 256), 512, 0, stream>>>(xn, wb_f, b_forget, nullptr, zf, 1024, 2048, sT, t0);
        // zi <- th = tanh(xn@Wi^T+b)           (RD=5)
        gemm_bt<5><<<dim3(8, Mc / 256), 512, 0, stream>>>(xn, wb_i, b_input,  nullptr, zi, 1024, 2048, sT, t0);
        scan_pass1<<<dim3(NSC, 4), 256, 0, stream>>>(zf, zi, Ach, Bch, T);
        scan_pass2<<<32, 256, 0, stream>>>(Ach, Bch, hst, hidden, state, hlast, NSC,
                                           (c == 0) ? 1 : 0, (c == NC - 1) ? 1 : 0);
        scan_pass3<<<dim3(NSC, 4), 256, 0, stream>>>(zf, zi, hst, T);
        gemm_bt<1><<<dim3(4, Mc / 256), 512, 0, stream>>>(zf, wb_h, b_hout, x, x1, 2048, 1024, sT, t0);
        // --- FFN SwiGLU sub-block ---
        rmsnorm_b16in<<<Mc, 256, 0, stream>>>(x1, g_norm2, xn);
        gemm_bt<0><<<dim3(8, Mc / 256), 512, 0, stream>>>(xn, wb_fc, b_fc,     nullptr, zf, 1024, 2048, sT, t0);
        // zf <- zf * silu(xn@Wfa^T+b)          (RD=3, SwiGLU fused)
        gemm_bt<3><<<dim3(8, Mc / 256), 512, 0, stream>>>(xn, wb_fa, b_fc_act, zf, zf, 1024, 2048, sT, t0);
        gemm_bt<2><<<dim3(4, Mc / 256), 512, 0, stream>>>(zf, wb_o, b_fout, x1, out, 2048, 1024, sT, t0);
    }
}